// Round 5
// baseline (1052.983 us; speedup 1.0000x reference)
//
#include <hip/hip_runtime.h>
#include <hip/hip_bf16.h>
#include <math.h>

#define BDIM 16384
#define HDIM 512

typedef __bf16 bf16;
typedef float f32x4 __attribute__((ext_vector_type(4)));
typedef __bf16 bf16x8 __attribute__((ext_vector_type(8)));
typedef __bf16 bf16x4 __attribute__((ext_vector_type(4)));

// ---------------------------------------------------------------- utilities

__device__ __forceinline__ void gload16(const bf16* g, bf16* l) {
  __builtin_amdgcn_global_load_lds((const __attribute__((address_space(1))) void*)g,
                                   (__attribute__((address_space(3))) void*)l, 16, 0, 0);
}
__device__ __forceinline__ void gload4(const bf16* g, bf16* l) {
  __builtin_amdgcn_global_load_lds((const __attribute__((address_space(1))) void*)g,
                                   (__attribute__((address_space(3))) void*)l, 4, 0, 0);
}

__device__ __forceinline__ float gelu_exact(float x) {
  return 0.5f * x * (1.0f + erff(x * 0.70710678118654752f));
}
__device__ __forceinline__ float gelu_fast(float x) {
  float u = x * (0.7978845608f + 0.0356774081f * x * x);
  float e = __expf(2.f * u);
  float t = 1.f - 2.f / (e + 1.f);
  return 0.5f * x * (1.f + t);
}

// ---------------------------------------------------------------- converts

__global__ void cvt_f32_bf16(const float* __restrict__ src, bf16* __restrict__ dst, int n4) {
  int i = blockIdx.x * blockDim.x + threadIdx.x;
  if (i >= n4) return;
  f32x4 v = *(const f32x4*)(src + (size_t)i * 4);
  bf16x4 o;
  o[0] = (bf16)v[0]; o[1] = (bf16)v[1]; o[2] = (bf16)v[2]; o[3] = (bf16)v[3];
  *(bf16x4*)(dst + (size_t)i * 4) = o;
}

// wvT[il][k][m] = wv[il][m][k]; wv = rows 1024..1535 of qkv block il ([1536][512])
__global__ void cvt_wvT(const float* __restrict__ qkv, bf16* __restrict__ dst) {
  __shared__ float t[32][33];
  int il = blockIdx.z;
  int bm = blockIdx.x * 32;
  int bk = blockIdx.y * 32;
  const float* s = qkv + (size_t)il * 786432 + 524288;
  int tx = threadIdx.x & 31, ty = threadIdx.x >> 5;
#pragma unroll
  for (int j = 0; j < 4; ++j)
    t[ty * 4 + j][tx] = s[(size_t)(bm + ty * 4 + j) * 512 + bk + tx];
  __syncthreads();
  bf16* d = dst + (size_t)il * 262144;
#pragma unroll
  for (int j = 0; j < 4; ++j)
    d[(size_t)(bk + ty * 4 + j) * 512 + bm + tx] = (bf16)t[tx][ty * 4 + j];
}

__global__ void zfill(float* __restrict__ p, int n) {
  int i = blockIdx.x * 256 + threadIdx.x;
  if (i < n) p[i] = 0.f;
}

// bc[il][n] = sum_m ao[il][n][m] * bv[il][m] + aob[il][n]
__global__ void bias_combine(const float* __restrict__ aow, const float* __restrict__ qkvb,
                             const float* __restrict__ aob, float* __restrict__ bc) {
  int gid = blockIdx.x * 4 + (threadIdx.x >> 6);
  int il = gid >> 9;
  int lane = threadIdx.x & 63;
  const float* ar = aow + (size_t)gid * 512 + lane * 8;
  const float* bv = qkvb + il * 1536 + 1024 + lane * 8;
  float s = 0.f;
#pragma unroll
  for (int i = 0; i < 8; ++i) s += ar[i] * bv[i];
#pragma unroll
  for (int off = 32; off > 0; off >>= 1) s += __shfl_xor(s, off);
  if (lane == 0) bc[gid] = s + aob[gid];
}

// ---------------------------------------------------------------- gemm_p2
// 128x256 tile, BK=32, 4 waves (1Mx4N), 3-slot ring 72KiB -> 2 blocks/CU,
// counted vmcnt, both-sides swizzle, setprio. C = act(A@W^T + bias).

template<int ACT, int K>
__launch_bounds__(256, 2)
__global__ void gemm_p2(const bf16* __restrict__ A, long long Az,
                        const bf16* __restrict__ W, long long Wz,
                        const float* __restrict__ bias, long long bz,
                        bf16* __restrict__ C, long long Cz, int ldc) {
  __shared__ bf16 lds[3][12288];   // slot: A[128][32] @0, B[256][32] @4096
  const long long z = blockIdx.z;
  A += z * Az; W += z * Wz; bias += z * bz; C += z * Cz;
  const int tid = threadIdx.x, lane = tid & 63, wid = tid >> 6;
  const int brow = blockIdx.x * 128, bcol = blockIdx.y * 256;
  const int wn = wid * 64, lr = lane & 15, kg = lane >> 4;
  const int ko = (kg ^ ((lr >> 1) & 3)) << 3;

  f32x4 acc[8][4] = {};

  // staging: unit = 256 thr x 16B = 64 rows x 32 cols; src slot pre-inverse-swizzled
  const int sco = (((tid & 3) ^ ((tid >> 3) & 3)) << 3);
  const bf16* Ag = A + (size_t)(brow + (tid >> 2)) * K + sco;
  const bf16* Wg = W + (size_t)(bcol + (tid >> 2)) * K + sco;
  auto SA = [&](int s, int kt, int u) {
    gload16(Ag + (size_t)u * 64 * K + kt * 32, &lds[s][u * 2048 + wid * 512]);
  };
  auto SB = [&](int s, int kt, int u) {
    gload16(Wg + (size_t)u * 64 * K + kt * 32, &lds[s][4096 + u * 2048 + wid * 512]);
  };

  const int nt = K / 32;
  SA(0,0,0); SA(0,0,1); SB(0,0,0); SB(0,0,1); SB(0,0,2); SB(0,0,3);
  SA(1,1,0); SA(1,1,1); SB(1,1,0); SB(1,1,1); SB(1,1,2); SB(1,1,3);

  int slot = 0;
  for (int t = 0; t < nt; ++t) {
    int s2 = slot + 2; if (s2 >= 3) s2 -= 3;
    const bf16* LA = &lds[slot][0];
    const bf16* LB = &lds[slot][4096];
    if (t + 2 < nt) { SA(s2,t+2,0); SA(s2,t+2,1); SB(s2,t+2,0); SB(s2,t+2,1); }
    if (t + 2 < nt)      asm volatile("s_waitcnt vmcnt(10)" ::: "memory");
    else if (t + 1 < nt) asm volatile("s_waitcnt vmcnt(6)" ::: "memory");
    else                 asm volatile("s_waitcnt vmcnt(0)" ::: "memory");
    __builtin_amdgcn_s_barrier();
    bf16x8 a[8], b0, b1;
#pragma unroll
    for (int m = 0; m < 8; ++m) a[m] = *(const bf16x8*)(LA + ((m*16+lr)<<5) + ko);
    b0 = *(const bf16x8*)(LB + ((wn + lr)<<5) + ko);
    b1 = *(const bf16x8*)(LB + ((wn + 16 + lr)<<5) + ko);
    __builtin_amdgcn_s_setprio(1);
#pragma unroll
    for (int m = 0; m < 8; ++m) {
      acc[m][0] = __builtin_amdgcn_mfma_f32_16x16x32_bf16(a[m], b0, acc[m][0], 0, 0, 0);
      acc[m][1] = __builtin_amdgcn_mfma_f32_16x16x32_bf16(a[m], b1, acc[m][1], 0, 0, 0);
    }
    __builtin_amdgcn_s_setprio(0);
    asm volatile("" ::: "memory");
    __builtin_amdgcn_s_barrier();
    if (t + 2 < nt) { SB(s2,t+2,2); SB(s2,t+2,3); }
    bf16x8 b2 = *(const bf16x8*)(LB + ((wn + 32 + lr)<<5) + ko);
    bf16x8 b3 = *(const bf16x8*)(LB + ((wn + 48 + lr)<<5) + ko);
    __builtin_amdgcn_s_setprio(1);
#pragma unroll
    for (int m = 0; m < 8; ++m) {
      acc[m][2] = __builtin_amdgcn_mfma_f32_16x16x32_bf16(a[m], b2, acc[m][2], 0, 0, 0);
      acc[m][3] = __builtin_amdgcn_mfma_f32_16x16x32_bf16(a[m], b3, acc[m][3], 0, 0, 0);
    }
    __builtin_amdgcn_s_setprio(0);
    asm volatile("" ::: "memory");
    __builtin_amdgcn_s_barrier();
    slot += 1; if (slot >= 3) slot = 0;
  }

  float bv[4];
#pragma unroll
  for (int n = 0; n < 4; ++n) bv[n] = bias[bcol + wn + n * 16 + lr];
#pragma unroll
  for (int m = 0; m < 8; ++m) {
    int row = brow + m * 16 + kg * 4;
#pragma unroll
    for (int n = 0; n < 4; ++n) {
      int col = bcol + wn + n * 16 + lr;
#pragma unroll
      for (int j = 0; j < 4; ++j) {
        float v = acc[m][n][j] + bv[n];
        if (ACT == 1) v = gelu_fast(v);
        C[(size_t)(row + j) * ldc + col] = (bf16)v;
      }
    }
  }
}

// ---------------------------------------------------------------- gemm_f
// BM=64 x BN=512 (full row), 8 waves (1Mx8N), 3-slot ring 108KiB.
// EPI 0: O = LN_A(acc+bias+R1)               (ip: R1=attn0; last f2: R1=xn)
// EPI 1: O = LN_B(LN_A(acc+bias+R1) + R2)    (mid f2: R1=xn, R2=attn_next)
// EPI 2: final output select/blend to f32 out (op)

template<int EPI, int K>
__launch_bounds__(512, 2)
__global__ void gemm_f(const bf16* __restrict__ A, long long Az,
                       const bf16* __restrict__ W, long long Wz,
                       const float* __restrict__ bias, long long bz,
                       const bf16* __restrict__ R1, long long R1z,
                       const bf16* __restrict__ R2,
                       const float* __restrict__ gA, const float* __restrict__ bA, long long gAz,
                       const float* __restrict__ gB, const float* __restrict__ bB,
                       bf16* __restrict__ O, long long Oz,
                       const float* __restrict__ imgF, const float* __restrict__ txtF,
                       const float* __restrict__ prior, const int* __restrict__ mt,
                       const float* __restrict__ rwp, float* __restrict__ outF) {
  __shared__ bf16 lds[3][18432];   // slot: A[64][32] @0, B[512][32] @2048
  const int z = blockIdx.z;
  A += (long long)z * Az; W += (long long)z * Wz; bias += (long long)z * bz;
  if (EPI <= 1) {
    R1 += (long long)z * R1z;
    gA += (long long)z * gAz; bA += (long long)z * gAz;
    O += (long long)z * Oz;
  }
  const int tid = threadIdx.x, lane = tid & 63, wid = tid >> 6;
  const int brow = blockIdx.x * 64;
  const int wn = wid * 64, lr = lane & 15, kg = lane >> 4;
  const int ko = (kg ^ ((lr >> 1) & 3)) << 3;

  f32x4 acc[4][4] = {};

  // A staging via gload4: unit = 512 thr x 4B = 32 rows x 32 cols (2 units)
  const int arow = tid >> 4;
  const int acol = ((((tid >> 2) & 3) ^ ((tid >> 5) & 3)) << 3) + ((tid & 3) * 2);
  const bf16* Ag = A + (size_t)(brow + arow) * K + acol;
  // B staging via gload16: unit = 512 thr x 16B = 128 rows x 32 cols (4 units)
  const int bco = (((tid & 3) ^ ((tid >> 3) & 3)) << 3);
  const bf16* Wg = W + (size_t)(tid >> 2) * K + bco;
  auto SA = [&](int s, int kt, int u) {
    gload4(Ag + (size_t)u * 32 * K + kt * 32, &lds[s][u * 1024 + wid * 128]);
  };
  auto SB = [&](int s, int kt, int u) {
    gload16(Wg + (size_t)u * 128 * K + kt * 32, &lds[s][2048 + u * 4096 + wid * 512]);
  };

  const int nt = K / 32;
  SA(0,0,0); SA(0,0,1); SB(0,0,0); SB(0,0,1); SB(0,0,2); SB(0,0,3);
  SA(1,1,0); SA(1,1,1); SB(1,1,0); SB(1,1,1); SB(1,1,2); SB(1,1,3);

  int slot = 0;
  for (int t = 0; t < nt; ++t) {
    int s2 = slot + 2; if (s2 >= 3) s2 -= 3;
    const bf16* LA = &lds[slot][0];
    const bf16* LB = &lds[slot][2048];
    if (t + 2 < nt) { SA(s2,t+2,0); SA(s2,t+2,1); SB(s2,t+2,0); SB(s2,t+2,1); }
    if (t + 2 < nt)      asm volatile("s_waitcnt vmcnt(10)" ::: "memory");
    else if (t + 1 < nt) asm volatile("s_waitcnt vmcnt(6)" ::: "memory");
    else                 asm volatile("s_waitcnt vmcnt(0)" ::: "memory");
    __builtin_amdgcn_s_barrier();
    bf16x8 a[4], b0, b1;
#pragma unroll
    for (int m = 0; m < 4; ++m) a[m] = *(const bf16x8*)(LA + ((m*16+lr)<<5) + ko);
    b0 = *(const bf16x8*)(LB + ((wn + lr)<<5) + ko);
    b1 = *(const bf16x8*)(LB + ((wn + 16 + lr)<<5) + ko);
    __builtin_amdgcn_s_setprio(1);
#pragma unroll
    for (int m = 0; m < 4; ++m) {
      acc[m][0] = __builtin_amdgcn_mfma_f32_16x16x32_bf16(a[m], b0, acc[m][0], 0, 0, 0);
      acc[m][1] = __builtin_amdgcn_mfma_f32_16x16x32_bf16(a[m], b1, acc[m][1], 0, 0, 0);
    }
    __builtin_amdgcn_s_setprio(0);
    asm volatile("" ::: "memory");
    __builtin_amdgcn_s_barrier();
    if (t + 2 < nt) { SB(s2,t+2,2); SB(s2,t+2,3); }
    bf16x8 b2 = *(const bf16x8*)(LB + ((wn + 32 + lr)<<5) + ko);
    bf16x8 b3 = *(const bf16x8*)(LB + ((wn + 48 + lr)<<5) + ko);
    __builtin_amdgcn_s_setprio(1);
#pragma unroll
    for (int m = 0; m < 4; ++m) {
      acc[m][2] = __builtin_amdgcn_mfma_f32_16x16x32_bf16(a[m], b2, acc[m][2], 0, 0, 0);
      acc[m][3] = __builtin_amdgcn_mfma_f32_16x16x32_bf16(a[m], b3, acc[m][3], 0, 0, 0);
    }
    __builtin_amdgcn_s_setprio(0);
    asm volatile("" ::: "memory");
    __builtin_amdgcn_s_barrier();
    slot += 1; if (slot >= 3) slot = 0;
  }

  float colb[4];
#pragma unroll
  for (int n = 0; n < 4; ++n) colb[n] = bias[wn + n * 16 + lr];

  if (EPI == 2) {
    // final: gen value -> select/blend -> f32 out
    float r = rwp[z];
    const float* basep = z ? imgF : txtF;
    const float* pr = prior + (z ? 0 : 512);
    float* op = outF + (z ? (size_t)0 : (size_t)BDIM * HDIM);
    const int want = z ? 2 : 1;
#pragma unroll
    for (int m = 0; m < 4; ++m) {
#pragma unroll
      for (int j = 0; j < 4; ++j) {
        int rglob = brow + m * 16 + kg * 4 + j;
        int msel = mt[rglob];
#pragma unroll
        for (int n = 0; n < 4; ++n) {
          int col = wn + n * 16 + lr;
          float v = acc[m][n][j] + colb[n];
          float base = basep[(size_t)rglob * HDIM + col];
          float o = base;
          if (msel == want) o = r * base + (1.f - r) * v;
          else if (msel == 3) o = pr[col];
          op[(size_t)rglob * HDIM + col] = o;
        }
      }
    }
    return;
  }

  // ---- LN path ----
  float gAv[4], bAv[4];
#pragma unroll
  for (int n = 0; n < 4; ++n) { gAv[n] = gA[wn + n*16 + lr]; bAv[n] = bA[wn + n*16 + lr]; }
  __syncthreads();
  float* red = (float*)&lds[0][0];   // [0..512) sums, [512..1024) sq, [1024..1152) stats, [1152..1280) stats2

  // pass A: v = acc + bias + R1; partial reduce per row
#pragma unroll
  for (int m = 0; m < 4; ++m) {
#pragma unroll
    for (int j = 0; j < 4; ++j) {
      int row = m * 16 + kg * 4 + j;
      int rglob = brow + row;
      float s = 0.f, q = 0.f;
#pragma unroll
      for (int n = 0; n < 4; ++n) {
        float v = acc[m][n][j] + colb[n] + (float)R1[(size_t)rglob * HDIM + wn + n*16 + lr];
        acc[m][n][j] = v;
        s += v; q += v * v;
      }
#pragma unroll
      for (int off = 1; off < 16; off <<= 1) { s += __shfl_xor(s, off); q += __shfl_xor(q, off); }
      if (lr == 0) { red[row * 8 + wid] = s; red[512 + row * 8 + wid] = q; }
    }
  }
  __syncthreads();
  if (tid < 64) {
    float s = 0.f, q = 0.f;
#pragma unroll
    for (int w = 0; w < 8; ++w) { s += red[tid * 8 + w]; q += red[512 + tid * 8 + w]; }
    float mean = s * (1.f / 512.f);
    float var = q * (1.f / 512.f) - mean * mean;
    red[1024 + tid * 2] = mean;
    red[1024 + tid * 2 + 1] = rsqrtf(var + 1e-5f);
  }
  __syncthreads();

  if (EPI == 0) {
#pragma unroll
    for (int m = 0; m < 4; ++m) {
#pragma unroll
      for (int j = 0; j < 4; ++j) {
        int row = m * 16 + kg * 4 + j;
        float mean = red[1024 + row * 2], rstd = red[1024 + row * 2 + 1];
#pragma unroll
        for (int n = 0; n < 4; ++n) {
          float t = (acc[m][n][j] - mean) * rstd * gAv[n] + bAv[n];
          O[(size_t)(brow + row) * HDIM + wn + n*16 + lr] = (bf16)t;
        }
      }
    }
    return;
  }

  // EPI == 1: second LN chain
  float gBv[4], bBv[4];
#pragma unroll
  for (int n = 0; n < 4; ++n) { gBv[n] = gB[wn + n*16 + lr]; bBv[n] = bB[wn + n*16 + lr]; }
#pragma unroll
  for (int m = 0; m < 4; ++m) {
#pragma unroll
    for (int j = 0; j < 4; ++j) {
      int row = m * 16 + kg * 4 + j;
      int rglob = brow + row;
      float mean = red[1024 + row * 2], rstd = red[1024 + row * 2 + 1];
      float s = 0.f, q = 0.f;
#pragma unroll
      for (int n = 0; n < 4; ++n) {
        float t = (acc[m][n][j] - mean) * rstd * gAv[n] + bAv[n]
                + (float)R2[(size_t)rglob * HDIM + wn + n*16 + lr];
        acc[m][n][j] = t;
        s += t; q += t * t;
      }
#pragma unroll
      for (int off = 1; off < 16; off <<= 1) { s += __shfl_xor(s, off); q += __shfl_xor(q, off); }
      if (lr == 0) { red[row * 8 + wid] = s; red[512 + row * 8 + wid] = q; }
    }
  }
  __syncthreads();
  if (tid < 64) {
    float s = 0.f, q = 0.f;
#pragma unroll
    for (int w = 0; w < 8; ++w) { s += red[tid * 8 + w]; q += red[512 + tid * 8 + w]; }
    float mean = s * (1.f / 512.f);
    float var = q * (1.f / 512.f) - mean * mean;
    red[1152 + tid * 2] = mean;
    red[1152 + tid * 2 + 1] = rsqrtf(var + 1e-5f);
  }
  __syncthreads();
#pragma unroll
  for (int m = 0; m < 4; ++m) {
#pragma unroll
    for (int j = 0; j < 4; ++j) {
      int row = m * 16 + kg * 4 + j;
      float mean = red[1152 + row * 2], rstd = red[1152 + row * 2 + 1];
#pragma unroll
      for (int n = 0; n < 4; ++n) {
        float o = (acc[m][n][j] - mean) * rstd * gBv[n] + bBv[n];
        O[(size_t)(brow + row) * HDIM + wn + n*16 + lr] = (bf16)o;
      }
    }
  }
}

// ---------------------------------------------------------------- GEMM 128x128 (tiny: Wc)

__launch_bounds__(256)
__global__ void gemm128(const bf16* __restrict__ A, long long Az, int lda,
                        const bf16* __restrict__ W, long long Wz,
                        const float* __restrict__ bias, long long bz,
                        bf16* __restrict__ C, long long Cz, int ldc, int K) {
  __shared__ bf16 As[128 * 64];
  __shared__ bf16 Bs[128 * 64];
  const long long z = blockIdx.z;
  A += z * Az; W += z * Wz; bias += z * bz; C += z * Cz;
  const int tid = threadIdx.x;
  const int lane = tid & 63;
  const int wid = tid >> 6;
  const int brow = blockIdx.x * 128;
  const int bcol = blockIdx.y * 128;
  const int wr = (wid >> 1) * 64;
  const int wc = (wid & 1) * 64;
  const int lr = lane & 15;
  const int kg = lane >> 4;
  f32x4 acc[4][4] = {};
  const bf16* Abase = A + (size_t)(brow + (tid >> 3)) * lda + ((tid & 7) << 3);
  const bf16* Wbase = W + (size_t)(bcol + (tid >> 3)) * K + ((tid & 7) << 3);
  bf16* AsDst = As + wid * 512;
  bf16* BsDst = Bs + wid * 512;
  for (int k0 = 0; k0 < K; k0 += 64) {
#pragma unroll
    for (int j = 0; j < 4; ++j) {
      gload16(Abase + (size_t)j * 32 * lda + k0, AsDst + j * 2048);
      gload16(Wbase + (size_t)j * 32 * K + k0, BsDst + j * 2048);
    }
    __syncthreads();
#pragma unroll
    for (int kk = 0; kk < 64; kk += 32) {
      bf16x8 a[4], bq[4];
#pragma unroll
      for (int m = 0; m < 4; ++m)
        a[m] = *(const bf16x8*)(As + (wr + m * 16 + lr) * 64 + kk + kg * 8);
#pragma unroll
      for (int n = 0; n < 4; ++n)
        bq[n] = *(const bf16x8*)(Bs + (wc + n * 16 + lr) * 64 + kk + kg * 8);
#pragma unroll
      for (int m = 0; m < 4; ++m)
#pragma unroll
        for (int n = 0; n < 4; ++n)
          acc[m][n] = __builtin_amdgcn_mfma_f32_16x16x32_bf16(a[m], bq[n], acc[m][n], 0, 0, 0);
    }
    __syncthreads();
  }
  float bv[4];
#pragma unroll
  for (int n = 0; n < 4; ++n) bv[n] = bias[bcol + wc + n * 16 + lr];
#pragma unroll
  for (int m = 0; m < 4; ++m) {
    int row = brow + wr + m * 16 + kg * 4;
#pragma unroll
    for (int n = 0; n < 4; ++n) {
      int col = bcol + wc + n * 16 + lr;
#pragma unroll
      for (int j = 0; j < 4; ++j)
        C[(size_t)(row + j) * ldc + col] = (bf16)(acc[m][n][j] + bv[n]);
    }
  }
}

// ---------------------------------------------------------------- prior MLP (tiny)

__global__ void prior_fc1(const float* __restrict__ emb, const float* __restrict__ w1,
                          const float* __restrict__ b1, float* __restrict__ h) {
  int j = blockIdx.x * 4 + (threadIdx.x >> 6);
  int lane = threadIdx.x & 63;
  const float* wr = w1 + (size_t)j * 512 + lane * 8;
  const float* e = emb + lane * 8;
  float s = 0.f;
#pragma unroll
  for (int i = 0; i < 8; ++i) s += e[i] * wr[i];
#pragma unroll
  for (int off = 32; off > 0; off >>= 1) s += __shfl_xor(s, off);
  if (lane == 0) h[j] = gelu_exact(s + b1[j]);
}

__global__ void prior_fc2(const float* __restrict__ h, const float* __restrict__ w2,
                          const float* __restrict__ b2, float* __restrict__ p) {
  int j = blockIdx.x * 4 + (threadIdx.x >> 6);
  int lane = threadIdx.x & 63;
  const float* wr = w2 + (size_t)j * 1024 + lane * 16;
  const float* e = h + lane * 16;
  float s = 0.f;
#pragma unroll
  for (int i = 0; i < 16; ++i) s += e[i] * wr[i];
#pragma unroll
  for (int off = 32; off > 0; off >>= 1) s += __shfl_xor(s, off);
  if (lane == 0) p[j] = s + b2[j];
}

// ---------------------------------------------------------------- launch

extern "C" void kernel_launch(void* const* d_in, const int* in_sizes, int n_in,
                              void* d_out, int out_size, void* d_ws, size_t ws_size,
                              hipStream_t stream) {
  const float* img  = (const float*)d_in[0];
  const float* txt  = (const float*)d_in[1];
  const float* ipw  = (const float*)d_in[2];
  const float* ipb  = (const float*)d_in[3];
  const float* qkvw = (const float*)d_in[4];
  const float* qkvb = (const float*)d_in[5];
  const float* aow  = (const float*)d_in[6];
  const float* aob  = (const float*)d_in[7];
  const float* ln1g = (const float*)d_in[8];
  const float* ln1b = (const float*)d_in[9];
  const float* ln2g = (const float*)d_in[10];
  const float* ln2b = (const float*)d_in[11];
  const float* f1w  = (const float*)d_in[12];
  const float* f1b  = (const float*)d_in[13];
  const float* f2w  = (const float*)d_in[14];
  const float* f2b  = (const float*)d_in[15];
  const float* opw  = (const float*)d_in[16];
  const float* opb  = (const float*)d_in[17];
  const float* rw   = (const float*)d_in[18];
  const float* pw1  = (const float*)d_in[19];
  const float* pb1  = (const float*)d_in[20];
  const float* pw2  = (const float*)d_in[21];
  const float* pb2  = (const float*)d_in[22];
  const float* pemb = (const float*)d_in[23];
  const int*   mt   = (const int*)d_in[24];
  float* out = (float*)d_out;

  const size_t B = BDIM;
  char* ws = (char*)d_ws;
  size_t off = 0;
  auto alloc = [&](size_t bytes) -> char* {
    char* p = ws + off;
    off += (bytes + 255) & ~(size_t)255;
    return p;
  };
  bf16* src_bf = (bf16*)alloc(2 * B * 512 * 2);           // [0]=img, [1]=txt
  bf16* ipw_bf = (bf16*)alloc((size_t)2 * 262144 * 2);
  bf16* wvT_bf = (bf16*)alloc((size_t)6 * 262144 * 2);
  bf16* ao_bf  = (bf16*)alloc((size_t)6 * 262144 * 2);
  bf16* f1_bf  = (bf16*)alloc((size_t)6 * 1048576 * 2);
  bf16* f2_bf  = (bf16*)alloc((size_t)6 * 1048576 * 2);
  bf16* op_bf  = (bf16*)alloc((size_t)2 * 262144 * 2);
  bf16* Wc_bf  = (bf16*)alloc((size_t)6 * 262144 * 2);
  float* bc    = (float*)alloc(6 * 512 * 4);
  float* zeros = (float*)alloc(512 * 4);
  float* ph    = (float*)alloc(1024 * 4);
  float* pout  = (float*)alloc(1024 * 4);
  bf16* xn     = (bf16*)alloc(2 * B * 512 * 2);
  bf16* bufA   = (bf16*)alloc(2 * B * 512 * 2);
  bf16* bufB   = (bf16*)alloc(2 * B * 512 * 2);
  bf16* h      = (bf16*)d_out;   // 16384x2048 bf16 == out_size f32 bytes; dead before final write

  auto cvt = [&](const float* s, bf16* d, size_t n) {
    int n4 = (int)(n / 4);
    cvt_f32_bf16<<<(n4 + 255) / 256, 256, 0, stream>>>(s, d, n4);
  };
  cvt(img, src_bf, B * 512);
  cvt(txt, src_bf + B * 512, B * 512);
  cvt(ipw, ipw_bf, 2 * 262144);
  cvt(aow, ao_bf, 6 * 262144);
  cvt(f1w, f1_bf, 6 * 1048576);
  cvt(f2w, f2_bf, 6 * 1048576);
  cvt(opw, op_bf, 2 * 262144);
  cvt_wvT<<<dim3(16, 16, 6), 256, 0, stream>>>(qkvw, wvT_bf);
  zfill<<<2, 256, 0, stream>>>(zeros, 512);
  bias_combine<<<768, 256, 0, stream>>>(aow, qkvb, aob, bc);
  gemm128<<<dim3(4, 4, 6), 256, 0, stream>>>(ao_bf, 262144, 512, wvT_bf, 262144,
                                             zeros, 0, Wc_bf, 262144, 512, 512);
  prior_fc1<<<256, 256, 0, stream>>>(pemb, pw1, pb1, ph);
  prior_fc2<<<256, 256, 0, stream>>>(ph, pw2, pb2, pout);

  const long long BS = (long long)B * 512;

  // attn_l = tgt @ Wc_l^T + bc_l  (z=0 -> tgt=txt, z=1 -> tgt=img)
  auto attn = [&](int l, bf16* dst) {
    gemm_p2<0, 512><<<dim3(128, 2, 2), 256, 0, stream>>>(
        src_bf + BS, -BS, Wc_bf + (size_t)l * 262144, 786432,
        bc + l * 512, 1536, dst, BS, 512);
  };
  attn(0, bufA);
  attn(1, bufB);

  // xn = LN1(src@ipw^T + ipb + attn0)
  gemm_f<0, 512><<<dim3(256, 1, 2), 512, 0, stream>>>(
      src_bf, BS, ipw_bf, 262144, ipb, 512,
      bufA, BS, nullptr,
      ln1g, ln1b, 1536, nullptr, nullptr,
      xn, BS, nullptr, nullptr, nullptr, nullptr, nullptr, nullptr);

  attn(2, bufA);   // after ip consumed bufA

  for (int l = 0; l < 3; ++l) {
    bf16* attnNext = (l == 0) ? bufB : bufA;   // attn_{l+1}
    for (int i = 0; i < 2; ++i) {
      size_t il = (size_t)i * 3 + l;
      // h = gelu(xn @ f1^T + b1)
      gemm_p2<1, 512><<<dim3(128, 8, 1), 256, 0, stream>>>(
          xn + (size_t)i * BS, 0, f1_bf + il * 1048576, 0,
          f1b + il * 2048, 0, h, 0, 2048);
      if (l < 2) {
        // xn = LN1( LN2(xn + h@f2^T + b2) + attn_{l+1} )
        gemm_f<1, 2048><<<dim3(256, 1, 1), 512, 0, stream>>>(
            h, 0, f2_bf + il * 1048576, 0, f2b + il * 512, 0,
            xn + (size_t)i * BS, 0, attnNext + (size_t)i * BS,
            ln2g + i * 1536 + l * 512, ln2b + i * 1536 + l * 512, 0,
            ln1g + i * 1536 + (l + 1) * 512, ln1b + i * 1536 + (l + 1) * 512,
            xn + (size_t)i * BS, 0,
            nullptr, nullptr, nullptr, nullptr, nullptr, nullptr);
      } else {
        // xn = LN2(xn + h@f2^T + b2)   (final x)
        gemm_f<0, 2048><<<dim3(256, 1, 1), 512, 0, stream>>>(
            h, 0, f2_bf + il * 1048576, 0, f2b + il * 512, 0,
            xn + (size_t)i * BS, 0, nullptr,
            ln2g + i * 1536 + l * 512, ln2b + i * 1536 + l * 512, 0,
            nullptr, nullptr,
            xn + (size_t)i * BS, 0,
            nullptr, nullptr, nullptr, nullptr, nullptr, nullptr);
      }
    }
  }

  // final: gen = xn @ opw^T + opb; select/blend -> out (z=0 text, z=1 img)
  gemm_f<2, 512><<<dim3(256, 1, 2), 512, 0, stream>>>(
      xn, BS, op_bf, 262144, opb, 512,
      nullptr, 0, nullptr,
      nullptr, nullptr, 0, nullptr, nullptr,
      nullptr, 0,
      img, txt, pout, mt, rw, out);
}